// Round 1
// baseline (2960.143 us; speedup 1.0000x reference)
//
#include <hip/hip_runtime.h>
#include <hip/hip_bf16.h>
#include <math.h>

// Problem constants
#define BB 128
#define TT 256
#define DV 1024
#define DA 128
#define HH 128
#define DF 512
#define KC 7
#define MM (BB*TT)   // 32768 rows

__device__ __forceinline__ float gelu_exact(float v) {
    return 0.5f * v * (1.0f + erff(v * 0.70710678118654752f));
}

// ---------------------------------------------------------------------------
// Classic fp32 tiled GEMM: C[M,N] = A[M,K] (row stride lda) @ B[K,N] + bias[N]
// 128x128 block tile, BK=8, 256 threads, 8x8 per thread (split 4+4 layout).
// GELU template flag applies exact gelu in epilogue.
// ---------------------------------------------------------------------------
template<int GELU>
__global__ __launch_bounds__(256) void sgemm(const float* __restrict__ A, int lda,
                                             const float* __restrict__ Bw,
                                             const float* __restrict__ bias,
                                             float* __restrict__ C,
                                             int M, int N, int K)
{
    __shared__ float As[8][128];
    __shared__ float Bs[8][132];

    const int bx = blockIdx.x, by = blockIdx.y;
    const int tid = threadIdx.x;
    const int tr = tid >> 4;        // 0..15
    const int tc = tid & 15;        // 0..15

    float acc[8][8];
#pragma unroll
    for (int i = 0; i < 8; ++i)
#pragma unroll
        for (int j = 0; j < 8; ++j) acc[i][j] = 0.0f;

    const int aRow = tid >> 1;          // 0..127
    const int aCol = (tid & 1) * 4;     // 0 or 4
    const int bRow = tid >> 5;          // 0..7
    const int bCol = (tid & 31) * 4;    // 0..124

    const float* Aptr = A + (size_t)(by * 128 + aRow) * lda + aCol;
    const float* Bptr = Bw + (size_t)bRow * N + bx * 128 + bCol;

    for (int k0 = 0; k0 < K; k0 += 8) {
        float4 av = *(const float4*)(Aptr + k0);
        float4 bv = *(const float4*)(Bptr + (size_t)k0 * N);
        __syncthreads();
        As[aCol + 0][aRow] = av.x;
        As[aCol + 1][aRow] = av.y;
        As[aCol + 2][aRow] = av.z;
        As[aCol + 3][aRow] = av.w;
        *(float4*)&Bs[bRow][bCol] = bv;
        __syncthreads();
#pragma unroll
        for (int kk = 0; kk < 8; ++kk) {
            float4 a0 = *(const float4*)&As[kk][tr * 4];
            float4 a1 = *(const float4*)&As[kk][tr * 4 + 64];
            float4 b0 = *(const float4*)&Bs[kk][tc * 4];
            float4 b1 = *(const float4*)&Bs[kk][tc * 4 + 64];
            float a[8] = {a0.x, a0.y, a0.z, a0.w, a1.x, a1.y, a1.z, a1.w};
            float b[8] = {b0.x, b0.y, b0.z, b0.w, b1.x, b1.y, b1.z, b1.w};
#pragma unroll
            for (int i = 0; i < 8; ++i)
#pragma unroll
                for (int j = 0; j < 8; ++j) acc[i][j] += a[i] * b[j];
        }
    }

    // epilogue
#pragma unroll
    for (int i = 0; i < 8; ++i) {
        int row = by * 128 + tr * 4 + (i & 3) + ((i >> 2) << 6);
        float* crow = C + (size_t)row * N + bx * 128;
#pragma unroll
        for (int jh = 0; jh < 2; ++jh) {
            int c0 = tc * 4 + jh * 64;
            float4 bv = *(const float4*)&bias[bx * 128 + c0];
            float4 o;
            o.x = acc[i][jh * 4 + 0] + bv.x;
            o.y = acc[i][jh * 4 + 1] + bv.y;
            o.z = acc[i][jh * 4 + 2] + bv.z;
            o.w = acc[i][jh * 4 + 3] + bv.w;
            if (GELU) {
                o.x = gelu_exact(o.x);
                o.y = gelu_exact(o.y);
                o.z = gelu_exact(o.z);
                o.w = gelu_exact(o.w);
            }
            *(float4*)&crow[c0] = o;
        }
    }
}

// ---------------------------------------------------------------------------
// Attention: per block = (one batch b, 32 query rows). scores in LDS,
// softmax, ctx = attn @ v. T=256, H=128.
// ---------------------------------------------------------------------------
__global__ __launch_bounds__(256) void attn_kernel(const float* __restrict__ q,
                                                   const float* __restrict__ k,
                                                   const float* __restrict__ v,
                                                   float* __restrict__ ctx)
{
    const int qt = blockIdx.x;   // 0..7  (32-row tile)
    const int b  = blockIdx.y;   // 0..127
    const int tid = threadIdx.x;

    __shared__ float sQ[32][130];
    __shared__ float sS[32][257];
    __shared__ float sKV[64][130];

    // load Q tile (32 x 128)
    const float* qbase = q + ((size_t)b * TT + qt * 32) * HH;
    for (int f = tid; f < 32 * 32; f += 256) {
        int r = f >> 5, c4 = f & 31;
        float4 val = ((const float4*)qbase)[f];
        sQ[r][c4 * 4 + 0] = val.x;
        sQ[r][c4 * 4 + 1] = val.y;
        sQ[r][c4 * 4 + 2] = val.z;
        sQ[r][c4 * 4 + 3] = val.w;
    }

    const int r = tid >> 3;   // 0..31 (query row in tile)
    const int g = tid & 7;    // 0..7

    const float qi = (float)(qt * 32 + r);
    const float scale = 0.08838834764831845f;  // 1/sqrt(128)

    // ---- scores ----
    for (int kt = 0; kt < 4; ++kt) {
        __syncthreads();   // prev sKV users done (and Q stores on first iter)
        const float* kbase = k + ((size_t)b * TT + kt * 64) * HH;
        for (int f = tid; f < 64 * 32; f += 256) {
            int rr = f >> 5, c4 = f & 31;
            float4 val = ((const float4*)kbase)[f];
            sKV[rr][c4 * 4 + 0] = val.x;
            sKV[rr][c4 * 4 + 1] = val.y;
            sKV[rr][c4 * 4 + 2] = val.z;
            sKV[rr][c4 * 4 + 3] = val.w;
        }
        __syncthreads();
        float acc[8] = {0, 0, 0, 0, 0, 0, 0, 0};
        for (int d2 = 0; d2 < 64; ++d2) {
            float2 qv = *(const float2*)&sQ[r][d2 * 2];
#pragma unroll
            for (int j = 0; j < 8; ++j) {
                int kj = j * 8 + g;
                float2 kv = *(const float2*)&sKV[kj][d2 * 2];
                acc[j] += qv.x * kv.x + qv.y * kv.y;
            }
        }
#pragma unroll
        for (int j = 0; j < 8; ++j) {
            int kjg = kt * 64 + j * 8 + g;
            float adj = expf(-fabsf(qi - (float)kjg) / 2.7182818284590452f);
            sS[r][kjg] = acc[j] * scale + adj;
        }
    }
    __syncthreads();

    // ---- softmax over each row (8 threads per row, 32 cols each) ----
    {
        float m = -1e30f;
        for (int c = 0; c < 32; ++c) m = fmaxf(m, sS[r][g * 32 + c]);
#pragma unroll
        for (int mask = 1; mask < 8; mask <<= 1) m = fmaxf(m, __shfl_xor(m, mask));
        float sum = 0.0f;
        for (int c = 0; c < 32; ++c) {
            float e = expf(sS[r][g * 32 + c] - m);
            sS[r][g * 32 + c] = e;
            sum += e;
        }
#pragma unroll
        for (int mask = 1; mask < 8; mask <<= 1) sum += __shfl_xor(sum, mask);
        float inv = 1.0f / sum;
        for (int c = 0; c < 32; ++c) sS[r][g * 32 + c] *= inv;
    }

    // ---- ctx = attn @ v ----
    const int dblk = tid & 7;  // column block: dblk*16 .. +15
    float acc2[16];
#pragma unroll
    for (int i = 0; i < 16; ++i) acc2[i] = 0.0f;

    for (int vt = 0; vt < 4; ++vt) {
        __syncthreads();   // softmax done / prev sKV users done
        const float* vbase = v + ((size_t)b * TT + vt * 64) * HH;
        for (int f = tid; f < 64 * 32; f += 256) {
            int rr = f >> 5, c4 = f & 31;
            float4 val = ((const float4*)vbase)[f];
            sKV[rr][c4 * 4 + 0] = val.x;
            sKV[rr][c4 * 4 + 1] = val.y;
            sKV[rr][c4 * 4 + 2] = val.z;
            sKV[rr][c4 * 4 + 3] = val.w;
        }
        __syncthreads();
        for (int kj = 0; kj < 64; ++kj) {
            float a = sS[r][vt * 64 + kj];
#pragma unroll
            for (int ii = 0; ii < 8; ++ii) {
                int jj = (ii + dblk) & 7;   // rotate to spread LDS banks
                float2 vv = *(const float2*)&sKV[kj][dblk * 16 + jj * 2];
                acc2[jj * 2 + 0] += a * vv.x;
                acc2[jj * 2 + 1] += a * vv.y;
            }
        }
    }

    float* cbase = ctx + ((size_t)b * TT + qt * 32 + r) * HH;
#pragma unroll
    for (int ii = 0; ii < 8; ++ii) {
        *(float2*)&cbase[dblk * 16 + ii * 2] = make_float2(acc2[ii * 2], acc2[ii * 2 + 1]);
    }
}

// ---------------------------------------------------------------------------
// Residual + LayerNorm: h = LN(fv + ca) * g + b    (in-place on ca buffer)
// one block per row, 256 threads, 4 floats each.
// ---------------------------------------------------------------------------
__global__ __launch_bounds__(256) void resln_kernel(const float* __restrict__ x,
                                                    float* __restrict__ hbuf,
                                                    const float* __restrict__ gam,
                                                    const float* __restrict__ bet)
{
    const int row = blockIdx.x;
    const int tid = threadIdx.x;
    const float4 f = *(const float4*)(x + (size_t)row * 1152 + tid * 4);
    const float4 c = *(const float4*)(hbuf + (size_t)row * 1024 + tid * 4);
    float4 h;
    h.x = f.x + c.x; h.y = f.y + c.y; h.z = f.z + c.z; h.w = f.w + c.w;

    float s  = h.x + h.y + h.z + h.w;
    float ss = h.x * h.x + h.y * h.y + h.z * h.z + h.w * h.w;
#pragma unroll
    for (int m = 1; m < 64; m <<= 1) {
        s  += __shfl_xor(s, m);
        ss += __shfl_xor(ss, m);
    }
    __shared__ float red[8];
    if ((tid & 63) == 0) {
        red[tid >> 6]     = s;
        red[4 + (tid >> 6)] = ss;
    }
    __syncthreads();
    s  = red[0] + red[1] + red[2] + red[3];
    ss = red[4] + red[5] + red[6] + red[7];
    const float mean = s * (1.0f / 1024.0f);
    const float var  = ss * (1.0f / 1024.0f) - mean * mean;
    const float rstd = 1.0f / sqrtf(var + 1e-5f);

    const float4 g4 = *(const float4*)(gam + tid * 4);
    const float4 b4 = *(const float4*)(bet + tid * 4);
    float4 o;
    o.x = (h.x - mean) * rstd * g4.x + b4.x;
    o.y = (h.y - mean) * rstd * g4.y + b4.y;
    o.z = (h.z - mean) * rstd * g4.z + b4.z;
    o.w = (h.w - mean) * rstd * g4.w + b4.w;
    *(float4*)(hbuf + (size_t)row * 1024 + tid * 4) = o;
}

// ---------------------------------------------------------------------------
// Causal conv (KC=7 taps over time) + sigmoid.
// block = (64 output t's, one batch). 256 threads: 4 i-range groups x 64 t.
// ---------------------------------------------------------------------------
__global__ __launch_bounds__(256) void conv_kernel(const float* __restrict__ h2,
                                                   const float* __restrict__ Wc,
                                                   const float* __restrict__ bcp,
                                                   float* __restrict__ out)
{
    const int t0 = blockIdx.x * 64;
    const int b  = blockIdx.y;
    const int tid = threadIdx.x;

    __shared__ float sw[896];
    __shared__ float sh[70][130];
    __shared__ float red[4][64];

    for (int i = tid; i < 896; i += 256) sw[i] = Wc[i];
    for (int f = tid; f < 70 * 32; f += 256) {
        int rr = f >> 5, c4 = f & 31;
        int trow = t0 - 6 + rr;
        float4 val = make_float4(0.f, 0.f, 0.f, 0.f);
        if (trow >= 0)
            val = *(const float4*)(h2 + ((size_t)b * TT + trow) * HH + c4 * 4);
        sh[rr][c4 * 4 + 0] = val.x;
        sh[rr][c4 * 4 + 1] = val.y;
        sh[rr][c4 * 4 + 2] = val.z;
        sh[rr][c4 * 4 + 3] = val.w;
    }
    __syncthreads();

    const int tt  = tid & 63;
    const int grp = tid >> 6;
    const int i0  = grp * 32;
    float acc = 0.0f;
    for (int j = 0; j < 7; ++j) {
        const int srow = tt + j;
#pragma unroll
        for (int i2 = 0; i2 < 16; ++i2) {
            float2 hv = *(const float2*)&sh[srow][i0 + i2 * 2];
            acc += hv.x * sw[(i0 + i2 * 2) * 7 + j] + hv.y * sw[(i0 + i2 * 2 + 1) * 7 + j];
        }
    }
    red[grp][tt] = acc;
    __syncthreads();
    if (grp == 0) {
        float tot = red[0][tt] + red[1][tt] + red[2][tt] + red[3][tt] + bcp[0];
        out[(size_t)b * TT + t0 + tt] = 1.0f / (1.0f + expf(-tot));
    }
}

// ---------------------------------------------------------------------------
extern "C" void kernel_launch(void* const* d_in, const int* in_sizes, int n_in,
                              void* d_out, int out_size, void* d_ws, size_t ws_size,
                              hipStream_t stream)
{
    const float* x   = (const float*)d_in[0];
    const float* Wq  = (const float*)d_in[1];
    const float* bq  = (const float*)d_in[2];
    const float* Wk  = (const float*)d_in[3];
    const float* bk  = (const float*)d_in[4];
    const float* Wv  = (const float*)d_in[5];
    const float* bv  = (const float*)d_in[6];
    const float* Wo  = (const float*)d_in[7];
    const float* bo  = (const float*)d_in[8];
    const float* lng = (const float*)d_in[9];
    const float* lnb = (const float*)d_in[10];
    const float* W1  = (const float*)d_in[11];
    const float* b1  = (const float*)d_in[12];
    const float* W2  = (const float*)d_in[13];
    const float* b2  = (const float*)d_in[14];
    const float* Wc  = (const float*)d_in[15];
    const float* bc  = (const float*)d_in[16];
    float* out = (float*)d_out;
    float* ws  = (float*)d_ws;

    const size_t MH = (size_t)MM * HH;      // 4.19M floats
    float* qb   = ws;
    float* kb   = ws + MH;
    float* vb   = ws + 2 * MH;
    float* ctx  = ws + 3 * MH;
    float* Ebuf = ws + 4 * MH;              // MM*1024 floats (ca -> h -> h2)
    float* hf   = ws;                       // reuse qb..ctx region (MM*512)
    float* h2   = Ebuf;                     // reuse after h consumed

    dim3 thr(256);
    // k = fv @ Wk + bk ; v = fv @ Wv + bv ; q = fa @ Wq + bq
    sgemm<0><<<dim3(1, 256), thr, 0, stream>>>(x,        1152, Wk, bk, kb, MM, HH, DV);
    sgemm<0><<<dim3(1, 256), thr, 0, stream>>>(x,        1152, Wv, bv, vb, MM, HH, DV);
    sgemm<0><<<dim3(1, 256), thr, 0, stream>>>(x + 1024, 1152, Wq, bq, qb, MM, HH, DA);
    // attention
    attn_kernel<<<dim3(8, 128), thr, 0, stream>>>(qb, kb, vb, ctx);
    // ca = ctx @ Wo + bo
    sgemm<0><<<dim3(8, 256), thr, 0, stream>>>(ctx, 128, Wo, bo, Ebuf, MM, DV, HH);
    // h = LN(fv + ca)
    resln_kernel<<<dim3(MM), thr, 0, stream>>>(x, Ebuf, lng, lnb);
    // hf = gelu(h @ W1 + b1)
    sgemm<1><<<dim3(4, 256), thr, 0, stream>>>(Ebuf, 1024, W1, b1, hf, MM, DF, DV);
    // h2 = hf @ W2 + b2
    sgemm<0><<<dim3(1, 256), thr, 0, stream>>>(hf, 512, W2, b2, h2, MM, HH, DF);
    // conv + sigmoid
    conv_kernel<<<dim3(4, 128), thr, 0, stream>>>(h2, Wc, bc, out);
}

// Round 5
// 728.002 us; speedup vs baseline: 4.0661x; 4.0661x over previous
//
#include <hip/hip_runtime.h>
#include <hip/hip_bf16.h>
#include <math.h>

// Problem constants
#define BB 128
#define TT 256
#define DV 1024
#define DA 128
#define HH 128
#define DF 512
#define KC 7
#define MM (BB*TT)   // 32768 rows

typedef __attribute__((ext_vector_type(8))) short short8v;   // 8 bf16 (4 VGPR)
typedef __attribute__((ext_vector_type(4))) float float4v;   // MFMA acc

__device__ __forceinline__ float gelu_exact(float v) {
    return 0.5f * v * (1.0f + erff(v * 0.70710678118654752f));
}
__device__ __forceinline__ ushort f2bf(float f) {            // RNE fp32->bf16
    unsigned u = __builtin_bit_cast(unsigned, f);
    unsigned r = u + 0x7FFFu + ((u >> 16) & 1u);
    return (ushort)(r >> 16);
}
__device__ __forceinline__ float bf2f(ushort h) {
    unsigned u = ((unsigned)h) << 16;
    return __builtin_bit_cast(float, u);
}

// ---------------------------------------------------------------------------
// Weight prepass: W[K][N] fp32 (row-major) -> Wt_hi/Wt_lo [N][K] bf16.
// grid (N/64, K/64), 256 threads, LDS-tiled transpose.
// ---------------------------------------------------------------------------
__global__ __launch_bounds__(256) void wconv_kernel(const float* __restrict__ W,
                                                    ushort* __restrict__ Th,
                                                    ushort* __restrict__ Tl,
                                                    int K, int N)
{
    __shared__ float sT[64][65];
    const int n0 = blockIdx.x * 64, k0 = blockIdx.y * 64;
    const int t = threadIdx.x;
    const int kk = t >> 4, n4 = (t & 15) * 4;
#pragma unroll
    for (int i = 0; i < 4; ++i) {
        float4 f = *(const float4*)(W + (size_t)(k0 + kk + i * 16) * N + n0 + n4);
        sT[kk + i * 16][n4 + 0] = f.x;
        sT[kk + i * 16][n4 + 1] = f.y;
        sT[kk + i * 16][n4 + 2] = f.z;
        sT[kk + i * 16][n4 + 3] = f.w;
    }
    __syncthreads();
    const int n = t >> 2, kq = (t & 3) * 16;
    ushort hh[16], ll[16];
#pragma unroll
    for (int j = 0; j < 16; ++j) {
        float v = sT[kq + j][n];
        ushort h = f2bf(v);
        hh[j] = h;
        ll[j] = f2bf(v - bf2f(h));
    }
    ushort* dh = Th + (size_t)(n0 + n) * K + k0 + kq;
    ushort* dl = Tl + (size_t)(n0 + n) * K + k0 + kq;
#pragma unroll
    for (int j = 0; j < 16; j += 4) {
        *(ushort4*)(dh + j) = make_ushort4(hh[j], hh[j+1], hh[j+2], hh[j+3]);
        *(ushort4*)(dl + j) = make_ushort4(ll[j], ll[j+1], ll[j+2], ll[j+3]);
    }
}

// ---------------------------------------------------------------------------
// Split-bf16 MFMA GEMM.  C[M,N] = A[M,K] @ W[K,N] + bias.
// A: fp32 (A_SPLIT=1, hi+lo split in-kernel, 3 MFMA/prod) or bf16 (A_SPLIT=0,
//    2 MFMA/prod).  B: pre-split Wt_hi/Wt_lo, [N][K] row-major (K contig).
// OUT_GELU_BF16: 0 -> fp32 C ; 1 -> gelu + bf16 C.
// Tile 128x128, BK=32, 256 thr = 4 waves (2x2 of 64x64), 16x16x32 MFMA.
// LDS layout [kgrp][row][8] so fragment ds_read_b128 is conflict-free.
// ---------------------------------------------------------------------------
template<int A_SPLIT, int OUT_GELU_BF16>
__global__ __launch_bounds__(256) void mgemm(const void* __restrict__ Av, int lda,
                                             const ushort* __restrict__ Bhg,
                                             const ushort* __restrict__ Blg,
                                             const float* __restrict__ bias,
                                             void* __restrict__ Cv,
                                             int N, int K)
{
    __shared__ ushort Ah[4][128][8];
    __shared__ ushort Al[4][128][8];
    __shared__ ushort Bh[4][128][8];
    __shared__ ushort Bl[4][128][8];

    const int tid = threadIdx.x;
    const int l = tid & 63;
    const int w = tid >> 6;
    const int wrow = (w >> 1) * 64, wcol = (w & 1) * 64;
    const int m0 = blockIdx.y * 128, n0 = blockIdx.x * 128;

    float4v acc[4][4];
#pragma unroll
    for (int m = 0; m < 4; ++m)
#pragma unroll
        for (int n = 0; n < 4; ++n) acc[m][n] = (float4v){0.f, 0.f, 0.f, 0.f};

    const int srow  = tid >> 1;          // staging row 0..127
    const int khalf = (tid & 1) * 16;    // k half 0 / 16

    for (int k0 = 0; k0 < K; k0 += 32) {
        __syncthreads();
        if (A_SPLIT) {
            const float* Ap = (const float*)Av + (size_t)(m0 + srow) * lda + k0 + khalf;
#pragma unroll
            for (int i = 0; i < 4; ++i) {
                float4 f = *(const float4*)(Ap + i * 4);
                ushort h0 = f2bf(f.x), h1 = f2bf(f.y), h2 = f2bf(f.z), h3 = f2bf(f.w);
                ushort l0 = f2bf(f.x - bf2f(h0)), l1 = f2bf(f.y - bf2f(h1));
                ushort l2 = f2bf(f.z - bf2f(h2)), l3 = f2bf(f.w - bf2f(h3));
                const int kg  = (khalf >> 3) + (i >> 1);
                const int off = (i & 1) * 4;
                *(ushort4*)&Ah[kg][srow][off] = make_ushort4(h0, h1, h2, h3);
                *(ushort4*)&Al[kg][srow][off] = make_ushort4(l0, l1, l2, l3);
            }
        } else {
            const ushort* Ap = (const ushort*)Av + (size_t)(m0 + srow) * lda + k0 + khalf;
#pragma unroll
            for (int i = 0; i < 2; ++i) {
                const int kg = (khalf >> 3) + i;
                *(short8v*)&Ah[kg][srow][0] = *(const short8v*)(Ap + i * 8);
            }
        }
        {
            const ushort* Bph = Bhg + (size_t)(n0 + srow) * K + k0 + khalf;
            const ushort* Bpl = Blg + (size_t)(n0 + srow) * K + k0 + khalf;
#pragma unroll
            for (int i = 0; i < 2; ++i) {
                const int kg = (khalf >> 3) + i;
                *(short8v*)&Bh[kg][srow][0] = *(const short8v*)(Bph + i * 8);
                *(short8v*)&Bl[kg][srow][0] = *(const short8v*)(Bpl + i * 8);
            }
        }
        __syncthreads();

        const int g = l >> 4, lr = l & 15;
        short8v af[4], alf[4], bfh[4], bfl[4];
#pragma unroll
        for (int m = 0; m < 4; ++m) {
            af[m] = *(const short8v*)&Ah[g][wrow + m * 16 + lr][0];
            if (A_SPLIT) alf[m] = *(const short8v*)&Al[g][wrow + m * 16 + lr][0];
        }
#pragma unroll
        for (int n = 0; n < 4; ++n) {
            bfh[n] = *(const short8v*)&Bh[g][wcol + n * 16 + lr][0];
            bfl[n] = *(const short8v*)&Bl[g][wcol + n * 16 + lr][0];
        }
#pragma unroll
        for (int m = 0; m < 4; ++m)
#pragma unroll
            for (int n = 0; n < 4; ++n) {
                acc[m][n] = __builtin_amdgcn_mfma_f32_16x16x32_bf16(af[m], bfh[n], acc[m][n], 0, 0, 0);
                acc[m][n] = __builtin_amdgcn_mfma_f32_16x16x32_bf16(af[m], bfl[n], acc[m][n], 0, 0, 0);
                if (A_SPLIT)
                    acc[m][n] = __builtin_amdgcn_mfma_f32_16x16x32_bf16(alf[m], bfh[n], acc[m][n], 0, 0, 0);
            }
    }

    // epilogue: C/D layout col = lane&15, row = (lane>>4)*4 + reg
    const int g = l >> 4, lr = l & 15;
#pragma unroll
    for (int n = 0; n < 4; ++n) {
        const int col = n0 + wcol + n * 16 + lr;
        const float bv = bias[col];
#pragma unroll
        for (int m = 0; m < 4; ++m) {
#pragma unroll
            for (int r = 0; r < 4; ++r) {
                const int row = m0 + wrow + m * 16 + g * 4 + r;
                float o = acc[m][n][r] + bv;
                if (OUT_GELU_BF16) {
                    ((ushort*)Cv)[(size_t)row * N + col] = f2bf(gelu_exact(o));
                } else {
                    ((float*)Cv)[(size_t)row * N + col] = o;
                }
            }
        }
    }
}

// ---------------------------------------------------------------------------
// Attention phase 1: S[b,q,k] = (Q.K) * scale + adj(q,k)
// ---------------------------------------------------------------------------
__global__ __launch_bounds__(256) void scores_kernel(const float* __restrict__ q,
                                                     const float* __restrict__ k,
                                                     float* __restrict__ S)
{
    const int kh = blockIdx.x;
    const int qh = blockIdx.y;
    const int b  = blockIdx.z;
    const int tid = threadIdx.x;
    const int tr = tid >> 4;
    const int tc = tid & 15;

    __shared__ float sA[32][68];
    __shared__ float sB[32][132];

    const float* Ab = q + ((size_t)b * TT + qh * 64) * HH;
    const float* Bb = k + ((size_t)b * TT + kh * 128) * HH;

    float acc[4][8];
#pragma unroll
    for (int i = 0; i < 4; ++i)
#pragma unroll
        for (int j = 0; j < 8; ++j) acc[i][j] = 0.0f;

    for (int k0 = 0; k0 < 128; k0 += 32) {
        __syncthreads();
#pragma unroll
        for (int ll = 0; ll < 2; ++ll) {
            int f = tid + ll * 256;
            int row = f >> 3, c4 = f & 7;
            float4 val = *(const float4*)(Ab + (size_t)row * HH + k0 + c4 * 4);
            sA[c4 * 4 + 0][row] = val.x;
            sA[c4 * 4 + 1][row] = val.y;
            sA[c4 * 4 + 2][row] = val.z;
            sA[c4 * 4 + 3][row] = val.w;
        }
#pragma unroll
        for (int ll = 0; ll < 4; ++ll) {
            int f = tid + ll * 256;
            int row = f >> 3, c4 = f & 7;
            float4 val = *(const float4*)(Bb + (size_t)row * HH + k0 + c4 * 4);
            sB[c4 * 4 + 0][row] = val.x;
            sB[c4 * 4 + 1][row] = val.y;
            sB[c4 * 4 + 2][row] = val.z;
            sB[c4 * 4 + 3][row] = val.w;
        }
        __syncthreads();
#pragma unroll
        for (int kk = 0; kk < 32; ++kk) {
            float4 a4 = *(const float4*)&sA[kk][tr * 4];
            float4 b0 = *(const float4*)&sB[kk][tc * 8];
            float4 b1 = *(const float4*)&sB[kk][tc * 8 + 4];
            float a[4]  = {a4.x, a4.y, a4.z, a4.w};
            float bb[8] = {b0.x, b0.y, b0.z, b0.w, b1.x, b1.y, b1.z, b1.w};
#pragma unroll
            for (int i = 0; i < 4; ++i)
#pragma unroll
                for (int j = 0; j < 8; ++j) acc[i][j] += a[i] * bb[j];
        }
    }

    const float scale = 0.088388347648318447f;   // 1/sqrt(128)
    const float inv_e = 0.36787944117144233f;    // 1/e
#pragma unroll
    for (int i = 0; i < 4; ++i) {
        int rq = qh * 64 + tr * 4 + i;
        float* srow = S + ((size_t)b * TT + rq) * TT + kh * 128 + tc * 8;
        float o[8];
#pragma unroll
        for (int j = 0; j < 8; ++j) {
            int ck = kh * 128 + tc * 8 + j;
            float adj = expf(-fabsf((float)(rq - ck)) * inv_e);
            o[j] = acc[i][j] * scale + adj;
        }
        *(float4*)srow       = make_float4(o[0], o[1], o[2], o[3]);
        *(float4*)(srow + 4) = make_float4(o[4], o[5], o[6], o[7]);
    }
}

// ---------------------------------------------------------------------------
// Attention phase 2: row softmax (in place), one wave per 256-el row.
// ---------------------------------------------------------------------------
__global__ __launch_bounds__(256) void softmax_kernel(float* __restrict__ S)
{
    const int row  = blockIdx.x * 4 + (threadIdx.x >> 6);
    const int lane = threadIdx.x & 63;
    float* p = S + (size_t)row * TT + lane * 4;
    float4 v = *(float4*)p;
    float m = fmaxf(fmaxf(v.x, v.y), fmaxf(v.z, v.w));
#pragma unroll
    for (int mask = 1; mask < 64; mask <<= 1) m = fmaxf(m, __shfl_xor(m, mask));
    float e0 = expf(v.x - m), e1 = expf(v.y - m), e2 = expf(v.z - m), e3 = expf(v.w - m);
    float s = e0 + e1 + e2 + e3;
#pragma unroll
    for (int mask = 1; mask < 64; mask <<= 1) s += __shfl_xor(s, mask);
    float inv = 1.0f / s;
    *(float4*)p = make_float4(e0 * inv, e1 * inv, e2 * inv, e3 * inv);
}

// ---------------------------------------------------------------------------
// Attention phase 3: ctx = S @ V, output stored as bf16 (feeds Wo mgemm).
// ---------------------------------------------------------------------------
__global__ __launch_bounds__(256) void pv_kernel(const float* __restrict__ S,
                                                 const float* __restrict__ v,
                                                 ushort* __restrict__ ctx)
{
    const int qh = blockIdx.x;
    const int b  = blockIdx.y;
    const int tid = threadIdx.x;
    const int tr = tid >> 4;
    const int tc = tid & 15;

    __shared__ float sA[32][68];
    __shared__ float sB[32][132];

    const float* Ab = S + ((size_t)b * TT + qh * 64) * TT;
    const float* Bb = v + (size_t)b * TT * HH;

    float acc[4][8];
#pragma unroll
    for (int i = 0; i < 4; ++i)
#pragma unroll
        for (int j = 0; j < 8; ++j) acc[i][j] = 0.0f;

    for (int k0 = 0; k0 < 256; k0 += 32) {
        __syncthreads();
#pragma unroll
        for (int ll = 0; ll < 2; ++ll) {
            int f = tid + ll * 256;
            int row = f >> 3, c4 = f & 7;
            float4 val = *(const float4*)(Ab + (size_t)row * TT + k0 + c4 * 4);
            sA[c4 * 4 + 0][row] = val.x;
            sA[c4 * 4 + 1][row] = val.y;
            sA[c4 * 4 + 2][row] = val.z;
            sA[c4 * 4 + 3][row] = val.w;
        }
#pragma unroll
        for (int ll = 0; ll < 4; ++ll) {
            int f = tid + ll * 256;
            int row = f >> 5, c4 = f & 31;
            float4 val = *(const float4*)(Bb + (size_t)(k0 + row) * HH + c4 * 4);
            *(float4*)&sB[row][c4 * 4] = val;
        }
        __syncthreads();
#pragma unroll
        for (int kk = 0; kk < 32; ++kk) {
            float4 a4 = *(const float4*)&sA[kk][tr * 4];
            float4 b0 = *(const float4*)&sB[kk][tc * 8];
            float4 b1 = *(const float4*)&sB[kk][tc * 8 + 4];
            float a[4]  = {a4.x, a4.y, a4.z, a4.w};
            float bb[8] = {b0.x, b0.y, b0.z, b0.w, b1.x, b1.y, b1.z, b1.w};
#pragma unroll
            for (int i = 0; i < 4; ++i)
#pragma unroll
                for (int j = 0; j < 8; ++j) acc[i][j] += a[i] * bb[j];
        }
    }

#pragma unroll
    for (int i = 0; i < 4; ++i) {
        ushort* crow = ctx + ((size_t)b * TT + qh * 64 + tr * 4 + i) * HH + tc * 8;
        *(ushort4*)crow = make_ushort4(f2bf(acc[i][0]), f2bf(acc[i][1]),
                                       f2bf(acc[i][2]), f2bf(acc[i][3]));
        *(ushort4*)(crow + 4) = make_ushort4(f2bf(acc[i][4]), f2bf(acc[i][5]),
                                             f2bf(acc[i][6]), f2bf(acc[i][7]));
    }
}

// ---------------------------------------------------------------------------
// Residual + LayerNorm: h = LN(fv + ca) * g + b   (in-place fp32)
// ---------------------------------------------------------------------------
__global__ __launch_bounds__(256) void resln_kernel(const float* __restrict__ x,
                                                    float* __restrict__ hbuf,
                                                    const float* __restrict__ gam,
                                                    const float* __restrict__ bet)
{
    const int row = blockIdx.x;
    const int tid = threadIdx.x;
    const float4 f = *(const float4*)(x + (size_t)row * 1152 + tid * 4);
    const float4 c = *(const float4*)(hbuf + (size_t)row * 1024 + tid * 4);
    float4 h;
    h.x = f.x + c.x; h.y = f.y + c.y; h.z = f.z + c.z; h.w = f.w + c.w;

    float s  = h.x + h.y + h.z + h.w;
    float ss = h.x * h.x + h.y * h.y + h.z * h.z + h.w * h.w;
#pragma unroll
    for (int m = 1; m < 64; m <<= 1) {
        s  += __shfl_xor(s, m);
        ss += __shfl_xor(ss, m);
    }
    __shared__ float red[8];
    if ((tid & 63) == 0) {
        red[tid >> 6]       = s;
        red[4 + (tid >> 6)] = ss;
    }
    __syncthreads();
    s  = red[0] + red[1] + red[2] + red[3];
    ss = red[4] + red[5] + red[6] + red[7];
    const float mean = s * (1.0f / 1024.0f);
    const float var  = ss * (1.0f / 1024.0f) - mean * mean;
    const float rstd = 1.0f / sqrtf(var + 1e-5f);

    const float4 g4 = *(const float4*)(gam + tid * 4);
    const float4 b4 = *(const float4*)(bet + tid * 4);
    float4 o;
    o.x = (h.x - mean) * rstd * g4.x + b4.x;
    o.y = (h.y - mean) * rstd * g4.y + b4.y;
    o.z = (h.z - mean) * rstd * g4.z + b4.z;
    o.w = (h.w - mean) * rstd * g4.w + b4.w;
    *(float4*)(hbuf + (size_t)row * 1024 + tid * 4) = o;
}

// ---------------------------------------------------------------------------
// Causal conv (KC=7) + sigmoid.
// ---------------------------------------------------------------------------
__global__ __launch_bounds__(256) void conv_kernel(const float* __restrict__ h2,
                                                   const float* __restrict__ Wc,
                                                   const float* __restrict__ bcp,
                                                   float* __restrict__ out)
{
    const int t0 = blockIdx.x * 64;
    const int b  = blockIdx.y;
    const int tid = threadIdx.x;

    __shared__ float sw[896];
    __shared__ float sh[70][130];
    __shared__ float red[4][64];

    for (int i = tid; i < 896; i += 256) sw[i] = Wc[i];
    for (int f = tid; f < 70 * 32; f += 256) {
        int rr = f >> 5, c4 = f & 31;
        int trow = t0 - 6 + rr;
        float4 val = make_float4(0.f, 0.f, 0.f, 0.f);
        if (trow >= 0)
            val = *(const float4*)(h2 + ((size_t)b * TT + trow) * HH + c4 * 4);
        sh[rr][c4 * 4 + 0] = val.x;
        sh[rr][c4 * 4 + 1] = val.y;
        sh[rr][c4 * 4 + 2] = val.z;
        sh[rr][c4 * 4 + 3] = val.w;
    }
    __syncthreads();

    const int tt  = tid & 63;
    const int grp = tid >> 6;
    const int i0  = grp * 32;
    float acc = 0.0f;
    for (int j = 0; j < 7; ++j) {
        const int srow2 = tt + j;
#pragma unroll
        for (int i2 = 0; i2 < 16; ++i2) {
            float2 hv = *(const float2*)&sh[srow2][i0 + i2 * 2];
            acc += hv.x * sw[(i0 + i2 * 2) * 7 + j] + hv.y * sw[(i0 + i2 * 2 + 1) * 7 + j];
        }
    }
    red[grp][tt] = acc;
    __syncthreads();
    if (grp == 0) {
        float tot = red[0][tt] + red[1][tt] + red[2][tt] + red[3][tt] + bcp[0];
        out[(size_t)b * TT + t0 + tt] = 1.0f / (1.0f + expf(-tot));
    }
}

// ---------------------------------------------------------------------------
extern "C" void kernel_launch(void* const* d_in, const int* in_sizes, int n_in,
                              void* d_out, int out_size, void* d_ws, size_t ws_size,
                              hipStream_t stream)
{
    const float* x   = (const float*)d_in[0];
    const float* Wq  = (const float*)d_in[1];
    const float* bq  = (const float*)d_in[2];
    const float* Wk  = (const float*)d_in[3];
    const float* bk  = (const float*)d_in[4];
    const float* Wv  = (const float*)d_in[5];
    const float* bv  = (const float*)d_in[6];
    const float* Wo  = (const float*)d_in[7];
    const float* bo  = (const float*)d_in[8];
    const float* lng = (const float*)d_in[9];
    const float* lnb = (const float*)d_in[10];
    const float* W1  = (const float*)d_in[11];
    const float* b1  = (const float*)d_in[12];
    const float* W2  = (const float*)d_in[13];
    const float* b2  = (const float*)d_in[14];
    const float* Wc  = (const float*)d_in[15];
    const float* bc  = (const float*)d_in[16];
    float* out = (float*)d_out;
    char* wsb = (char*)d_ws;

    // ---- workspace map (peak 197.0 MB; round-1 footprint was 201.3 MB) ----
    ushort* WT   = (ushort*)wsb;                        // [0, 4.0M) weight splits
    const size_t oWq_h = 0,       oWq_l = 16384;
    const size_t oWk_h = 32768,   oWk_l = 163840;
    const size_t oWv_h = 294912,  oWv_l = 425984;
    const size_t oWo_h = 557056,  oWo_l = 688128;
    const size_t oW1_h = 819200,  oW1_l = 1343488;
    const size_t oW2_h = 1867776, oW2_l = 1933312;
    float*  qb   = (float*)(wsb + 4194304);             // [4.0M, 20.8M)
    float*  kb   = qb + 4194304;                        // [20.8M, 37.6M)
    float*  vb   = kb + 4194304;                        // [37.6M, 54.5M)
    ushort* ctxb = (ushort*)(wsb + 54525952);           // [54.5M, 62.9M) bf16
    float*  Ebuf = (float*)(wsb + 62914560);            // [62.9M, 197.0M) S/ca/h
    float*  Sbuf = Ebuf;
    ushort* hf   = (ushort*)(wsb + 4194304);            // reuse qb/kb (bf16, 33.5M)
    float*  h2   = (float*)(wsb + 37748736);            // reuse vb (16.8M)

    dim3 thr(256);
    // ---- weight transpose + hi/lo split prepass (grid = (N/64, K/64)) ----
    wconv_kernel<<<dim3(2, 2),  thr, 0, stream>>>(Wq, WT + oWq_h, WT + oWq_l, 128, 128);
    wconv_kernel<<<dim3(2, 16), thr, 0, stream>>>(Wk, WT + oWk_h, WT + oWk_l, 1024, 128);
    wconv_kernel<<<dim3(2, 16), thr, 0, stream>>>(Wv, WT + oWv_h, WT + oWv_l, 1024, 128);
    wconv_kernel<<<dim3(16, 2), thr, 0, stream>>>(Wo, WT + oWo_h, WT + oWo_l, 128, 1024);
    wconv_kernel<<<dim3(8, 16), thr, 0, stream>>>(W1, WT + oW1_h, WT + oW1_l, 1024, 512);
    wconv_kernel<<<dim3(2, 8),  thr, 0, stream>>>(W2, WT + oW2_h, WT + oW2_l, 512, 128);

    // ---- projections: k,v from fv; q from fa (A fp32-split, 3-prod) ----
    mgemm<1, 0><<<dim3(1, 256), thr, 0, stream>>>(x,        1152, WT + oWk_h, WT + oWk_l, bk, kb, 128, 1024);
    mgemm<1, 0><<<dim3(1, 256), thr, 0, stream>>>(x,        1152, WT + oWv_h, WT + oWv_l, bv, vb, 128, 1024);
    mgemm<1, 0><<<dim3(1, 256), thr, 0, stream>>>(x + 1024, 1152, WT + oWq_h, WT + oWq_l, bq, qb, 128, 128);
    // ---- attention ----
    scores_kernel <<<dim3(2, 4, 128), thr, 0, stream>>>(qb, kb, Sbuf);
    softmax_kernel<<<dim3(MM / 4),    thr, 0, stream>>>(Sbuf);
    pv_kernel     <<<dim3(4, 128),    thr, 0, stream>>>(Sbuf, vb, ctxb);
    // ---- ca = ctx @ Wo + bo (A bf16 direct, 2-prod) ----
    mgemm<0, 0><<<dim3(8, 256), thr, 0, stream>>>(ctxb, 128, WT + oWo_h, WT + oWo_l, bo, Ebuf, 1024, 128);
    // ---- h = LN(fv + ca) ----
    resln_kernel<<<dim3(MM), thr, 0, stream>>>(x, Ebuf, lng, lnb);
    // ---- hf = gelu(h @ W1 + b1) -> bf16 (A fp32-split) ----
    mgemm<1, 1><<<dim3(4, 256), thr, 0, stream>>>(Ebuf, 1024, WT + oW1_h, WT + oW1_l, b1, hf, 512, 1024);
    // ---- h2 = hf @ W2 + b2 (A bf16 direct) ----
    mgemm<0, 0><<<dim3(1, 256), thr, 0, stream>>>(hf, 512, WT + oW2_h, WT + oW2_l, b2, h2, 128, 512);
    // ---- conv + sigmoid ----
    conv_kernel<<<dim3(4, 128), thr, 0, stream>>>(h2, Wc, bc, out);
}

// Round 9
// 568.805 us; speedup vs baseline: 5.2041x; 1.2799x over previous
//
#include <hip/hip_runtime.h>
#include <hip/hip_bf16.h>
#include <math.h>

// Problem constants
#define BB 128
#define TT 256
#define DV 1024
#define DA 128
#define HH 128
#define DF 512
#define KC 7
#define MM (BB*TT)   // 32768 rows

typedef __attribute__((ext_vector_type(8))) short    short8v;  // 8x16b LDS stage
typedef __attribute__((ext_vector_type(8))) _Float16 half8v;   // MFMA A/B frag
typedef __attribute__((ext_vector_type(4))) float    float4v;  // MFMA acc

__device__ __forceinline__ float gelu_exact(float v) {
    return 0.5f * v * (1.0f + erff(v * 0.70710678118654752f));
}
__device__ __forceinline__ ushort f2h(float f) {   // RNE fp32->fp16
    _Float16 h = (_Float16)f;
    return __builtin_bit_cast(ushort, h);
}
__device__ __forceinline__ float h2f(ushort u) {
    _Float16 h = __builtin_bit_cast(_Float16, u);
    return (float)h;
}

// ---------------------------------------------------------------------------
// Weight prepass: W[K][N] fp32 (row-major) -> Wt [N][K] fp16.
// grid (N/64, K/64), 256 threads, LDS-tiled transpose.
// ---------------------------------------------------------------------------
__global__ __launch_bounds__(256) void wconv_kernel(const float* __restrict__ W,
                                                    ushort* __restrict__ Th,
                                                    int K, int N)
{
    __shared__ float sT[64][65];
    const int n0 = blockIdx.x * 64, k0 = blockIdx.y * 64;
    const int t = threadIdx.x;
    const int kk = t >> 4, n4 = (t & 15) * 4;
#pragma unroll
    for (int i = 0; i < 4; ++i) {
        float4 f = *(const float4*)(W + (size_t)(k0 + kk + i * 16) * N + n0 + n4);
        sT[kk + i * 16][n4 + 0] = f.x;
        sT[kk + i * 16][n4 + 1] = f.y;
        sT[kk + i * 16][n4 + 2] = f.z;
        sT[kk + i * 16][n4 + 3] = f.w;
    }
    __syncthreads();
    const int n = t >> 2, kq = (t & 3) * 16;
    ushort hh[16];
#pragma unroll
    for (int j = 0; j < 16; ++j) hh[j] = f2h(sT[kq + j][n]);
    ushort* dh = Th + (size_t)(n0 + n) * K + k0 + kq;
#pragma unroll
    for (int j = 0; j < 16; j += 4)
        *(ushort4*)(dh + j) = make_ushort4(hh[j], hh[j+1], hh[j+2], hh[j+3]);
}

// ---------------------------------------------------------------------------
// fp16 MFMA GEMM.  C[M,N] = A[M,K] @ W[K,N] + bias.
// BM: 128 (4 waves 2x2, 64x64/wave) or 64 (4 waves 2x2, 32x64/wave).
// A_F32: 1 -> A fp32, convert to fp16 while staging; 0 -> A already fp16.
// B: fp16 [N][K] row-major (K contiguous).
// OUT: 0 -> fp32 C ; 1 -> gelu + fp16 C ; 2 -> fp16 C.
// BK=32, 16x16x32 MFMA.  LDS [kgrp][row][8] -> conflict-light ds_read_b128.
// ---------------------------------------------------------------------------
template<int BM, int A_F32, int OUT>
__global__ __launch_bounds__(256) void mgemm(const void* __restrict__ Av, int lda,
                                             const ushort* __restrict__ Bt,
                                             const float* __restrict__ bias,
                                             void* __restrict__ Cv,
                                             int N, int K)
{
    constexpr int MF = BM / 32;              // m-fragments per wave
    __shared__ ushort Ah[4][BM][8];
    __shared__ ushort Bh[4][128][8];

    const int tid = threadIdx.x;
    const int l = tid & 63;
    const int w = tid >> 6;
    const int wrow = (w >> 1) * (MF * 16), wcol = (w & 1) * 64;
    const int m0 = blockIdx.y * BM, n0 = blockIdx.x * 128;

    float4v acc[MF][4];
#pragma unroll
    for (int m = 0; m < MF; ++m)
#pragma unroll
        for (int n = 0; n < 4; ++n) acc[m][n] = (float4v){0.f, 0.f, 0.f, 0.f};

    for (int k0 = 0; k0 < K; k0 += 32) {
        __syncthreads();
        // ---- stage A ----
        if (A_F32) {
            if (BM == 128) {
                const int srow = tid >> 1, kh = (tid & 1) * 16;
                const float* Ap = (const float*)Av + (size_t)(m0 + srow) * lda + k0 + kh;
#pragma unroll
                for (int i = 0; i < 4; ++i) {
                    float4 f = *(const float4*)(Ap + i * 4);
                    *(ushort4*)&Ah[(kh >> 3) + (i >> 1)][srow][(i & 1) * 4] =
                        make_ushort4(f2h(f.x), f2h(f.y), f2h(f.z), f2h(f.w));
                }
            } else {
                const int srow = tid >> 2, ko = (tid & 3) * 8;
                const float* Ap = (const float*)Av + (size_t)(m0 + srow) * lda + k0 + ko;
#pragma unroll
                for (int i = 0; i < 2; ++i) {
                    float4 f = *(const float4*)(Ap + i * 4);
                    *(ushort4*)&Ah[ko >> 3][srow][i * 4] =
                        make_ushort4(f2h(f.x), f2h(f.y), f2h(f.z), f2h(f.w));
                }
            }
        } else {
            if (BM == 128) {
                const int srow = tid >> 1, kh = (tid & 1) * 16;
                const ushort* Ap = (const ushort*)Av + (size_t)(m0 + srow) * lda + k0 + kh;
                *(short8v*)&Ah[(kh >> 3) + 0][srow][0] = *(const short8v*)(Ap + 0);
                *(short8v*)&Ah[(kh >> 3) + 1][srow][0] = *(const short8v*)(Ap + 8);
            } else {
                const int srow = tid >> 2, ko = (tid & 3) * 8;
                const ushort* Ap = (const ushort*)Av + (size_t)(m0 + srow) * lda + k0 + ko;
                *(short8v*)&Ah[ko >> 3][srow][0] = *(const short8v*)Ap;
            }
        }
        // ---- stage B ----
        {
            const int srow = tid >> 1, kh = (tid & 1) * 16;
            const ushort* Bp = Bt + (size_t)(n0 + srow) * K + k0 + kh;
            *(short8v*)&Bh[(kh >> 3) + 0][srow][0] = *(const short8v*)(Bp + 0);
            *(short8v*)&Bh[(kh >> 3) + 1][srow][0] = *(const short8v*)(Bp + 8);
        }
        __syncthreads();

        const int g = l >> 4, lr = l & 15;
        half8v af[MF], bf_[4];
#pragma unroll
        for (int m = 0; m < MF; ++m)
            af[m] = *(const half8v*)&Ah[g][wrow + m * 16 + lr][0];
#pragma unroll
        for (int n = 0; n < 4; ++n)
            bf_[n] = *(const half8v*)&Bh[g][wcol + n * 16 + lr][0];
#pragma unroll
        for (int m = 0; m < MF; ++m)
#pragma unroll
            for (int n = 0; n < 4; ++n)
                acc[m][n] = __builtin_amdgcn_mfma_f32_16x16x32_f16(af[m], bf_[n], acc[m][n], 0, 0, 0);
    }

    // epilogue: C/D layout col = lane&15, row = (lane>>4)*4 + reg
    const int g = l >> 4, lr = l & 15;
#pragma unroll
    for (int n = 0; n < 4; ++n) {
        const int col = n0 + wcol + n * 16 + lr;
        const float bv = bias[col];
#pragma unroll
        for (int m = 0; m < MF; ++m) {
#pragma unroll
            for (int r = 0; r < 4; ++r) {
                const int row = m0 + wrow + m * 16 + g * 4 + r;
                float o = acc[m][n][r] + bv;
                if (OUT == 0)      ((float*)Cv)[(size_t)row * N + col] = o;
                else if (OUT == 1) ((ushort*)Cv)[(size_t)row * N + col] = f2h(gelu_exact(o));
                else               ((ushort*)Cv)[(size_t)row * N + col] = f2h(o);
            }
        }
    }
}

// ---------------------------------------------------------------------------
// Attention phase 1: S[b,q,k] = (Q.K) * scale + adj(q,k)
// ---------------------------------------------------------------------------
__global__ __launch_bounds__(256) void scores_kernel(const float* __restrict__ q,
                                                     const float* __restrict__ k,
                                                     float* __restrict__ S)
{
    const int kh = blockIdx.x;
    const int qh = blockIdx.y;
    const int b  = blockIdx.z;
    const int tid = threadIdx.x;
    const int tr = tid >> 4;
    const int tc = tid & 15;

    __shared__ float sA[32][68];
    __shared__ float sB[32][132];

    const float* Ab = q + ((size_t)b * TT + qh * 64) * HH;
    const float* Bb = k + ((size_t)b * TT + kh * 128) * HH;

    float acc[4][8];
#pragma unroll
    for (int i = 0; i < 4; ++i)
#pragma unroll
        for (int j = 0; j < 8; ++j) acc[i][j] = 0.0f;

    for (int k0 = 0; k0 < 128; k0 += 32) {
        __syncthreads();
#pragma unroll
        for (int ll = 0; ll < 2; ++ll) {
            int f = tid + ll * 256;
            int row = f >> 3, c4 = f & 7;
            float4 val = *(const float4*)(Ab + (size_t)row * HH + k0 + c4 * 4);
            sA[c4 * 4 + 0][row] = val.x;
            sA[c4 * 4 + 1][row] = val.y;
            sA[c4 * 4 + 2][row] = val.z;
            sA[c4 * 4 + 3][row] = val.w;
        }
#pragma unroll
        for (int ll = 0; ll < 4; ++ll) {
            int f = tid + ll * 256;
            int row = f >> 3, c4 = f & 7;
            float4 val = *(const float4*)(Bb + (size_t)row * HH + k0 + c4 * 4);
            sB[c4 * 4 + 0][row] = val.x;
            sB[c4 * 4 + 1][row] = val.y;
            sB[c4 * 4 + 2][row] = val.z;
            sB[c4 * 4 + 3][row] = val.w;
        }
        __syncthreads();
#pragma unroll
        for (int kk = 0; kk < 32; ++kk) {
            float4 a4 = *(const float4*)&sA[kk][tr * 4];
            float4 b0 = *(const float4*)&sB[kk][tc * 8];
            float4 b1 = *(const float4*)&sB[kk][tc * 8 + 4];
            float a[4]  = {a4.x, a4.y, a4.z, a4.w};
            float bb[8] = {b0.x, b0.y, b0.z, b0.w, b1.x, b1.y, b1.z, b1.w};
#pragma unroll
            for (int i = 0; i < 4; ++i)
#pragma unroll
                for (int j = 0; j < 8; ++j) acc[i][j] += a[i] * bb[j];
        }
    }

    const float scale = 0.088388347648318447f;   // 1/sqrt(128)
    const float inv_e = 0.36787944117144233f;    // 1/e
#pragma unroll
    for (int i = 0; i < 4; ++i) {
        int rq = qh * 64 + tr * 4 + i;
        float* srow = S + ((size_t)b * TT + rq) * TT + kh * 128 + tc * 8;
        float o[8];
#pragma unroll
        for (int j = 0; j < 8; ++j) {
            int ck = kh * 128 + tc * 8 + j;
            float adj = expf(-fabsf((float)(rq - ck)) * inv_e);
            o[j] = acc[i][j] * scale + adj;
        }
        *(float4*)srow       = make_float4(o[0], o[1], o[2], o[3]);
        *(float4*)(srow + 4) = make_float4(o[4], o[5], o[6], o[7]);
    }
}

// ---------------------------------------------------------------------------
// Attention phase 2: row softmax (in place), one wave per 256-el row.
// ---------------------------------------------------------------------------
__global__ __launch_bounds__(256) void softmax_kernel(float* __restrict__ S)
{
    const int row  = blockIdx.x * 4 + (threadIdx.x >> 6);
    const int lane = threadIdx.x & 63;
    float* p = S + (size_t)row * TT + lane * 4;
    float4 v = *(float4*)p;
    float m = fmaxf(fmaxf(v.x, v.y), fmaxf(v.z, v.w));
#pragma unroll
    for (int mask = 1; mask < 64; mask <<= 1) m = fmaxf(m, __shfl_xor(m, mask));
    float e0 = expf(v.x - m), e1 = expf(v.y - m), e2 = expf(v.z - m), e3 = expf(v.w - m);
    float s = e0 + e1 + e2 + e3;
#pragma unroll
    for (int mask = 1; mask < 64; mask <<= 1) s += __shfl_xor(s, mask);
    float inv = 1.0f / s;
    *(float4*)p = make_float4(e0 * inv, e1 * inv, e2 * inv, e3 * inv);
}

// ---------------------------------------------------------------------------
// Attention phase 3: ctx = S @ V, output stored fp16 (feeds Wo mgemm).
// ---------------------------------------------------------------------------
__global__ __launch_bounds__(256) void pv_kernel(const float* __restrict__ S,
                                                 const float* __restrict__ v,
                                                 ushort* __restrict__ ctx)
{
    const int qh = blockIdx.x;
    const int b  = blockIdx.y;
    const int tid = threadIdx.x;
    const int tr = tid >> 4;
    const int tc = tid & 15;

    __shared__ float sA[32][68];
    __shared__ float sB[32][132];

    const float* Ab = S + ((size_t)b * TT + qh * 64) * TT;
    const float* Bb = v + (size_t)b * TT * HH;

    float acc[4][8];
#pragma unroll
    for (int i = 0; i < 4; ++i)
#pragma unroll
        for (int j = 0; j < 8; ++j) acc[i][j] = 0.0f;

    for (int k0 = 0; k0 < 256; k0 += 32) {
        __syncthreads();
#pragma unroll
        for (int ll = 0; ll < 2; ++ll) {
            int f = tid + ll * 256;
            int row = f >> 3, c4 = f & 7;
            float4 val = *(const float4*)(Ab + (size_t)row * TT + k0 + c4 * 4);
            sA[c4 * 4 + 0][row] = val.x;
            sA[c4 * 4 + 1][row] = val.y;
            sA[c4 * 4 + 2][row] = val.z;
            sA[c4 * 4 + 3][row] = val.w;
        }
#pragma unroll
        for (int ll = 0; ll < 4; ++ll) {
            int f = tid + ll * 256;
            int row = f >> 5, c4 = f & 31;
            float4 val = *(const float4*)(Bb + (size_t)(k0 + row) * HH + c4 * 4);
            *(float4*)&sB[row][c4 * 4] = val;
        }
        __syncthreads();
#pragma unroll
        for (int kk = 0; kk < 32; ++kk) {
            float4 a4 = *(const float4*)&sA[kk][tr * 4];
            float4 b0 = *(const float4*)&sB[kk][tc * 8];
            float4 b1 = *(const float4*)&sB[kk][tc * 8 + 4];
            float a[4]  = {a4.x, a4.y, a4.z, a4.w};
            float bb[8] = {b0.x, b0.y, b0.z, b0.w, b1.x, b1.y, b1.z, b1.w};
#pragma unroll
            for (int i = 0; i < 4; ++i)
#pragma unroll
                for (int j = 0; j < 8; ++j) acc[i][j] += a[i] * bb[j];
        }
    }

#pragma unroll
    for (int i = 0; i < 4; ++i) {
        ushort* crow = ctx + ((size_t)b * TT + qh * 64 + tr * 4 + i) * HH + tc * 8;
        *(ushort4*)crow       = make_ushort4(f2h(acc[i][0]), f2h(acc[i][1]),
                                             f2h(acc[i][2]), f2h(acc[i][3]));
        *(ushort4*)(crow + 4) = make_ushort4(f2h(acc[i][4]), f2h(acc[i][5]),
                                             f2h(acc[i][6]), f2h(acc[i][7]));
    }
}

// ---------------------------------------------------------------------------
// Residual + LayerNorm: h = LN(fv + ca16) * g + b -> fp16 into a SEPARATE
// buffer (no in-place dtype compaction -> no cross-block aliasing race).
// ---------------------------------------------------------------------------
__global__ __launch_bounds__(256) void resln_kernel(const float* __restrict__ x,
                                                    const ushort* __restrict__ ca16,
                                                    ushort* __restrict__ h16,
                                                    const float* __restrict__ gam,
                                                    const float* __restrict__ bet)
{
    const int row = blockIdx.x;
    const int tid = threadIdx.x;
    const float4 f = *(const float4*)(x + (size_t)row * 1152 + tid * 4);
    const ushort4 c4v = *(const ushort4*)(ca16 + (size_t)row * 1024 + tid * 4);
    float4 h;
    h.x = f.x + h2f(c4v.x); h.y = f.y + h2f(c4v.y);
    h.z = f.z + h2f(c4v.z); h.w = f.w + h2f(c4v.w);

    float s  = h.x + h.y + h.z + h.w;
    float ss = h.x * h.x + h.y * h.y + h.z * h.z + h.w * h.w;
#pragma unroll
    for (int m = 1; m < 64; m <<= 1) {
        s  += __shfl_xor(s, m);
        ss += __shfl_xor(ss, m);
    }
    __shared__ float red[8];
    if ((tid & 63) == 0) {
        red[tid >> 6]       = s;
        red[4 + (tid >> 6)] = ss;
    }
    __syncthreads();
    s  = red[0] + red[1] + red[2] + red[3];
    ss = red[4] + red[5] + red[6] + red[7];
    const float mean = s * (1.0f / 1024.0f);
    const float var  = ss * (1.0f / 1024.0f) - mean * mean;
    const float rstd = 1.0f / sqrtf(var + 1e-5f);

    const float4 g4 = *(const float4*)(gam + tid * 4);
    const float4 b4 = *(const float4*)(bet + tid * 4);
    ushort* hout = h16 + (size_t)row * 1024 + tid * 4;
    *(ushort4*)hout = make_ushort4(
        f2h((h.x - mean) * rstd * g4.x + b4.x),
        f2h((h.y - mean) * rstd * g4.y + b4.y),
        f2h((h.z - mean) * rstd * g4.z + b4.z),
        f2h((h.w - mean) * rstd * g4.w + b4.w));
}

// ---------------------------------------------------------------------------
// Causal conv (KC=7) + sigmoid.
// ---------------------------------------------------------------------------
__global__ __launch_bounds__(256) void conv_kernel(const float* __restrict__ h2,
                                                   const float* __restrict__ Wc,
                                                   const float* __restrict__ bcp,
                                                   float* __restrict__ out)
{
    const int t0 = blockIdx.x * 64;
    const int b  = blockIdx.y;
    const int tid = threadIdx.x;

    __shared__ float sw[896];
    __shared__ float sh[70][130];
    __shared__ float red[4][64];

    for (int i = tid; i < 896; i += 256) sw[i] = Wc[i];
    for (int f = tid; f < 70 * 32; f += 256) {
        int rr = f >> 5, c4 = f & 31;
        int trow = t0 - 6 + rr;
        float4 val = make_float4(0.f, 0.f, 0.f, 0.f);
        if (trow >= 0)
            val = *(const float4*)(h2 + ((size_t)b * TT + trow) * HH + c4 * 4);
        sh[rr][c4 * 4 + 0] = val.x;
        sh[rr][c4 * 4 + 1] = val.y;
        sh[rr][c4 * 4 + 2] = val.z;
        sh[rr][c4 * 4 + 3] = val.w;
    }
    __syncthreads();

    const int tt  = tid & 63;
    const int grp = tid >> 6;
    const int i0  = grp * 32;
    float acc = 0.0f;
    for (int j = 0; j < 7; ++j) {
        const int srow2 = tt + j;
#pragma unroll
        for (int i2 = 0; i2 < 16; ++i2) {
            float2 hv = *(const float2*)&sh[srow2][i0 + i2 * 2];
            acc += hv.x * sw[(i0 + i2 * 2) * 7 + j] + hv.y * sw[(i0 + i2 * 2 + 1) * 7 + j];
        }
    }
    red[grp][tt] = acc;
    __syncthreads();
    if (grp == 0) {
        float tot = red[0][tt] + red[1][tt] + red[2][tt] + red[3][tt] + bcp[0];
        out[(size_t)b * TT + t0 + tt] = 1.0f / (1.0f + expf(-tot));
    }
}

// ---------------------------------------------------------------------------
extern "C" void kernel_launch(void* const* d_in, const int* in_sizes, int n_in,
                              void* d_out, int out_size, void* d_ws, size_t ws_size,
                              hipStream_t stream)
{
    const float* x   = (const float*)d_in[0];
    const float* Wq  = (const float*)d_in[1];
    const float* bq  = (const float*)d_in[2];
    const float* Wk  = (const float*)d_in[3];
    const float* bk  = (const float*)d_in[4];
    const float* Wv  = (const float*)d_in[5];
    const float* bv  = (const float*)d_in[6];
    const float* Wo  = (const float*)d_in[7];
    const float* bo  = (const float*)d_in[8];
    const float* lng = (const float*)d_in[9];
    const float* lnb = (const float*)d_in[10];
    const float* W1  = (const float*)d_in[11];
    const float* b1  = (const float*)d_in[12];
    const float* W2  = (const float*)d_in[13];
    const float* b2  = (const float*)d_in[14];
    const float* Wc  = (const float*)d_in[15];
    const float* bc  = (const float*)d_in[16];
    float* out = (float*)d_out;
    char* wsb = (char*)d_ws;

    // ---- workspace map (peak 197.1 MB; proven ws >= 201.3 MB) ----
    ushort* WT   = (ushort*)wsb;                        // [0, 2.0M) fp16 weights [N][K]
    const size_t oWq = 0,      oWk = 16384,  oWv = 147456;
    const size_t oWo = 278528, oW1 = 409600, oW2 = 933888;
    float*  qb   = (float*)(wsb + 4194304);             // [4.2M, 21.0M) fp32
    float*  kb   = qb + 4194304;                        // [21.0M, 37.7M)
    float*  vb   = kb + 4194304;                        // [37.7M, 54.5M)
    ushort* ctxb = (ushort*)(wsb + 54525952);           // [54.5M, 62.9M) fp16
    float*  Sbuf = (float*)(wsb + 62914560);            // [62.9M, 96.5M) fp32 scores
    ushort* ca16 = (ushort*)(wsb + 62914560);           // [62.9M, 130.0M) fp16 ca (after S dead)
    ushort* h16  = (ushort*)(wsb + 130023424);          // [130.0M, 197.1M) fp16 h
    ushort* hf   = (ushort*)(wsb + 4194304);            // reuse qb/kb (fp16, 33.5M)
    float*  h2   = (float*)(wsb + 37748736);            // reuse vb (fp32, 16.8M)

    dim3 thr(256);
    // ---- weight transpose + fp16 convert prepass (grid = (N/64, K/64)) ----
    wconv_kernel<<<dim3(2, 2),  thr, 0, stream>>>(Wq, WT + oWq, 128, 128);
    wconv_kernel<<<dim3(2, 16), thr, 0, stream>>>(Wk, WT + oWk, 1024, 128);
    wconv_kernel<<<dim3(2, 16), thr, 0, stream>>>(Wv, WT + oWv, 1024, 128);
    wconv_kernel<<<dim3(16, 2), thr, 0, stream>>>(Wo, WT + oWo, 128, 1024);
    wconv_kernel<<<dim3(8, 16), thr, 0, stream>>>(W1, WT + oW1, 1024, 512);
    wconv_kernel<<<dim3(2, 8),  thr, 0, stream>>>(W2, WT + oW2, 512, 128);

    // ---- projections (A = fp32 x, BM=64 for occupancy) ----
    mgemm<64, 1, 0><<<dim3(1, 512), thr, 0, stream>>>(x,        1152, WT + oWk, bk, kb, 128, 1024);
    mgemm<64, 1, 0><<<dim3(1, 512), thr, 0, stream>>>(x,        1152, WT + oWv, bv, vb, 128, 1024);
    mgemm<64, 1, 0><<<dim3(1, 512), thr, 0, stream>>>(x + 1024, 1152, WT + oWq, bq, qb, 128, 128);
    // ---- attention ----
    scores_kernel <<<dim3(2, 4, 128), thr, 0, stream>>>(qb, kb, Sbuf);
    softmax_kernel<<<dim3(MM / 4),    thr, 0, stream>>>(Sbuf);
    pv_kernel     <<<dim3(4, 128),    thr, 0, stream>>>(Sbuf, vb, ctxb);
    // ---- ca16 = ctx @ Wo + bo -> fp16 (A fp16) ----
    mgemm<128, 0, 2><<<dim3(8, 256), thr, 0, stream>>>(ctxb, 128, WT + oWo, bo, ca16, 1024, 128);
    // ---- h16 = LN(fv + ca16) -> fp16 (separate buffer) ----
    resln_kernel<<<dim3(MM), thr, 0, stream>>>(x, ca16, h16, lng, lnb);
    // ---- hf = gelu(h @ W1 + b1) -> fp16 (A fp16) ----
    mgemm<128, 0, 1><<<dim3(4, 256), thr, 0, stream>>>(h16, 1024, WT + oW1, b1, hf, 512, 1024);
    // ---- h2 = hf @ W2 + b2 -> fp32 (A fp16, BM=64) ----
    mgemm<64, 0, 0><<<dim3(1, 512), thr, 0, stream>>>(hf, 512, WT + oW2, b2, h2, 128, 512);
    // ---- conv + sigmoid ----
    conv_kernel<<<dim3(4, 128), thr, 0, stream>>>(h2, Wc, bc, out);
}